// Round 20
// baseline (606.489 us; speedup 1.0000x reference)
//
#include <hip/hip_runtime.h>
#include <hip/hip_bf16.h>

// PointCloudNetPersistencePrediction — round 20: duals to 8 waves/SIMD.
// R19 flat: small-kernel fusion saves ~0 (boundary cost is per BIG apply).
// Remaining 4-waves/SIMD kernels: the 8 duals ((512,4), ~70 VGPR). Fix:
// dual s=1 m-subtile (M=16, grid (128,16)=2048 blocks), ~45 VGPR -> fits
// 64-reg budget -> launch_bounds(512,8) = 8 waves/SIMD (R12->R14 showed
// this hot loop gains ~10% from 4->8 waves). LDS 16 KB (red aliases stage).
// Downside bounded: VGPR overflow just reverts occupancy to today's 4.

#define NN 2048
#define NPAIR 16

typedef _Float16 half8 __attribute__((ext_vector_type(8)));
typedef _Float16 f16x2 __attribute__((ext_vector_type(2)));
typedef float f32x4 __attribute__((ext_vector_type(4)));

extern "C" __device__ f16x2 __ocml_exp2_2f16(f16x2);   // packed v_exp_f16

#define C2F 0.28853900817779268f   //  0.2 * log2(e)
#define CWF -0.14426950408889634f  // -0.1 * log2(e)
#define NL2T 3.3219280948873623f   // -log2(0.1); qi' = qi + NL2T

// ---- init+pack fused: Xs fp32 [p][i][{x,y,z,q}]; XT fp16 [p][16][2048]
//      (row3 = ones -> deg via MFMA); Xp packed fp16 j-pair entries ----
__global__ __launch_bounds__(256) void initpack_k(const float* __restrict__ pc,
                                                  const float* __restrict__ alphas,
                                                  float* __restrict__ Xs,
                                                  _Float16* __restrict__ XT,
                                                  _Float16* __restrict__ Xp) {
    int gid = blockIdx.x * 256 + threadIdx.x;
    if (gid >= NPAIR * NN) return;
    int p = gid >> 11, i = gid & (NN - 1);
    int b = p >> 2, k = p & 3;
    const float* pcr = pc + ((size_t)b * NN + i) * 3;
    const float* al  = alphas + k * 3;
    float x = pcr[0] * al[0], y = pcr[1] * al[1], z = pcr[2] * al[2];
    float q = CWF * (x * x + y * y + z * z);
    float4 o; o.x = x; o.y = y; o.z = z; o.w = q;
    ((float4*)Xs)[gid] = o;
    _Float16* xt = XT + (size_t)p * 16 * NN + i;
    xt[0 * NN] = (_Float16)x;
    xt[1 * NN] = (_Float16)y;
    xt[2 * NN] = (_Float16)z;
    xt[3 * NN] = (_Float16)1.0f;
#pragma unroll
    for (int n = 4; n < 16; ++n) xt[n * NN] = (_Float16)0.f;
    _Float16* xp = Xp + ((size_t)p * 1024 + (i >> 1)) * 8 + (i & 1);
    xp[0] = (_Float16)x; xp[2] = (_Float16)y;
    xp[4] = (_Float16)z; xp[6] = (_Float16)q;
}

// ---- fused apply: out = f16(0.5*cur + ihd (x) (W@cur^T)^T).
// 512 thr = 8 K-waves (chunk 256). Singles: s=2 subtiles, M=32, grid (64,16),
// 8 waves/SIMD. DUAL: s=1, M=16, grid (128,16), 8 waves/SIMD; shared w-eval
// feeds both banks' MFMAs. BUILDU: step-8 epilogue also emits UT rows.
template<bool FIRST, bool DUAL, bool BUILDU>
__global__ __launch_bounds__(512, 8)
void apply_k(const float* __restrict__ Xs, const _Float16* __restrict__ Xp,
             float* __restrict__ ihd,
             const _Float16* __restrict__ cur1, _Float16* __restrict__ out1,
             float* __restrict__ lvl1, int t1,
             const _Float16* __restrict__ cur2, _Float16* __restrict__ out2,
             float* __restrict__ lvl2, int t2,
             const float* __restrict__ LT1u, _Float16* __restrict__ UTp) {
    constexpr int S = DUAL ? 1 : 2;                // m-subtiles per lane
    constexpr int SMSZ = BUILDU ? 4352 : 4096;     // floats
    __shared__ __align__(16) float smem[SMSZ];
    const int tid  = threadIdx.x;
    const int lane = tid & 63;
    const int wv   = tid >> 6;                     // K-group 0..7
    const int p    = blockIdx.y;
    const int m0   = blockIdx.x * (16 * S);
    const int idx16 = lane & 15, quad = lane >> 4;

    {
        const float4* src = (const float4*)(Xp + (size_t)p * 8192);
        float4* dst = (float4*)smem;
        dst[tid]       = src[tid];
        dst[tid + 512] = src[tid + 512];
    }
    __syncthreads();

    f16x2 qi2[S], xx2[S], xy2[S], xz2[S];
#pragma unroll
    for (int s = 0; s < S; ++s) {
        float4 v = *(const float4*)(Xs + ((size_t)p * NN + m0 + s * 16 + idx16) * 4);
        _Float16 q = (_Float16)(v.w + NL2T);
        _Float16 x = (_Float16)(C2F * v.x);
        _Float16 y = (_Float16)(C2F * v.y);
        _Float16 z = (_Float16)(C2F * v.z);
        qi2[s] = (f16x2){q, q}; xx2[s] = (f16x2){x, x};
        xy2[s] = (f16x2){y, y}; xz2[s] = (f16x2){z, z};
    }
    const f16x2 SC2 = (f16x2){(_Float16)32768.f, (_Float16)32768.f};

    const _Float16* bp1 = cur1 + ((size_t)p * 16 + idx16) * NN + wv * 256 + quad * 8;
    const _Float16* bp2 = DUAL ? cur2 + ((size_t)p * 16 + idx16) * NN + wv * 256 + quad * 8
                               : nullptr;
    f32x4 acc1[S], acc2[S];
#pragma unroll
    for (int s = 0; s < S; ++s) {
        acc1[s] = (f32x4){0.f, 0.f, 0.f, 0.f};
        acc2[s] = (f32x4){0.f, 0.f, 0.f, 0.f};
    }

    for (int kc = 0; kc < 8; ++kc) {
        const int pb = wv * 128 + kc * 16 + quad * 4;  // j-pair entry base
        half8 bf1 = *(const half8*)(bp1 + kc * 32);
        half8 bf2;
        if (DUAL) bf2 = *(const half8*)(bp2 + kc * 32);
        union { f16x2 h2[4]; half8 h8; } af[S];
#pragma unroll
        for (int jp = 0; jp < 4; ++jp) {
            union { float4 f; f16x2 h[4]; } e;
            e.f = ((const float4*)smem)[pb + jp];      // {x2,y2,z2,q2} for 2 j
#pragma unroll
            for (int s = 0; s < S; ++s) {
                f16x2 tv = qi2[s] + e.h[3];
                tv = __builtin_elementwise_fma(xx2[s], e.h[0], tv);
                tv = __builtin_elementwise_fma(xy2[s], e.h[1], tv);
                tv = __builtin_elementwise_fma(xz2[s], e.h[2], tv);
                // threshold folded into exp arg: t'<0 -> arg<=-24 -> exp2 = 0
                f16x2 u = __builtin_elementwise_min(tv, tv * SC2);
                af[s].h2[jp] = __ocml_exp2_2f16(u);    // = 10*w (2^3.32 fold)
            }
        }
#pragma unroll
        for (int s = 0; s < S; ++s) {
            acc1[s] = __builtin_amdgcn_mfma_f32_16x16x32_f16(af[s].h8, bf1, acc1[s], 0, 0, 0);
            if (DUAL)
                acc2[s] = __builtin_amdgcn_mfma_f32_16x16x32_f16(af[s].h8, bf2, acc2[s], 0, 0, 0);
        }
    }

    // ---- epilogue: red region aliases dead X stage ----
    // bank1 partials at [0 .. 8*256*S), bank2 (dual) at [2048 .. 4096)
    __syncthreads();
#pragma unroll
    for (int s = 0; s < S; ++s)
        *(f32x4*)&smem[wv * (256 * S) + s * 256 + lane * 4] = acc1[s];
    if (DUAL)
        *(f32x4*)&smem[2048 + wv * 256 + lane * 4] = acc2[0];
    __syncthreads();

    const int n = tid & 15, rloc = tid >> 4;
    float o1v = 0.f;
    if (tid < 256 * S) {
        const int mloc = rloc & 15;
        const int base = (S == 2 ? (rloc >> 4) * 256 : 0)
                       + (mloc >> 2) * 64 + (mloc & 3);
        const int row = m0 + rloc;
        float ihEff;
        if (!FIRST) ihEff = 0.1f * ihd[p * NN + row];
        {
            float sum = 0.f;                           // = 10*(W@B)
#pragma unroll
            for (int g = 0; g < 8; ++g) sum += smem[g * (256 * S) + base + n * 4];
            if (FIRST) {
                float deg10 = 0.f;                     // = 10*deg
#pragma unroll
                for (int g = 0; g < 8; ++g) deg10 += smem[g * (256 * S) + base + 12];
                float ih = 5.0f / deg10;               // = 0.5/deg
                if (n == 3) ihd[p * NN + row] = ih;
                ihEff = 0.1f * ih;
            }
            float cv = (float)cur1[((size_t)p * 16 + n) * NN + row];
            o1v = 0.5f * cv + ihEff * sum;
            out1[((size_t)p * 16 + n) * NN + row] = (_Float16)o1v;
            if (lvl1) lvl1[(((size_t)p * 5 + t1) * 16 + n) * NN + row] = o1v;
        }
        if (DUAL) {
            float sum = 0.f;
#pragma unroll
            for (int g = 0; g < 8; ++g) sum += smem[2048 + g * 256 + base + n * 4];
            float cv = (float)cur2[((size_t)p * 16 + n) * NN + row];
            float o = 0.5f * cv + ihEff * sum;
            out2[((size_t)p * 16 + n) * NN + row] = (_Float16)o;
            if (lvl2) lvl2[(((size_t)p * 5 + t2) * 16 + n) * NN + row] = o;
        }
    }
    if (BUILDU) {
        // stash fresh t=8 (cols 0-2) then emit this block's UT rows
        const int row = m0 + rloc;
        if (n < 3) smem[4096 + n * 32 + rloc] = o1v;
        __syncthreads();
        _Float16 uv = (_Float16)0.f;
        if (n < 12) {
            const int jw = n / 3, c = n - 3 * jw;
            float a = (jw == 0) ? Xs[((size_t)p * NN + row) * 4 + c]
                                : LT1u[(((size_t)p * 5 + (jw - 1)) * 16 + c) * NN + row];
            float bb = (jw == 3) ? smem[4096 + c * 32 + rloc]
                                 : LT1u[(((size_t)p * 5 + jw) * 16 + c) * NN + row];
            uv = (_Float16)fabsf(a - bb);
        }
        UTp[((size_t)p * 16 + n) * NN + row] = uv;
    }
}

// ---- final mean over N of 48 features (levels [p][t][n][m]) ----
__global__ __launch_bounds__(64) void reduce_k(const float* __restrict__ Xs,
                                               const float* __restrict__ LT1,
                                               const float* __restrict__ LT2,
                                               float* __restrict__ out) {
    int f = blockIdx.x, p = blockIdx.y, lane = threadIdx.x;
    const float* l1 = LT1 + (size_t)p * 5 * 16 * NN;
    const float* l2 = LT2 + (size_t)p * 5 * 16 * NN;
    float s = 0.f;
    for (int m = lane; m < NN; m += 64) {
        float v;
        if (f < 3) {
            v = l1[((size_t)4 * 16 + f) * NN + m];
        } else if (f < 18) {
            int j = (f - 3) / 3, c = (f - 3) % 3;
            float a = (j == 0) ? Xs[((size_t)p * NN + m) * 4 + c]
                               : l1[((size_t)(j - 1) * 16 + c) * NN + m];
            float b = l1[((size_t)j * 16 + c) * NN + m];
            v = fabsf(a - b);
        } else {
            int gg = f - 18, j2, uc;
            if (gg < 3)       { j2 = 1; uc = gg; }
            else if (gg < 9)  { j2 = 2; uc = gg - 3; }
            else if (gg < 18) { j2 = 3; uc = gg - 9; }
            else              { j2 = 4; uc = gg - 18; }
            v = fabsf(l2[((size_t)(j2 - 1) * 16 + uc) * NN + m]
                    - l2[((size_t)j2 * 16 + uc) * NN + m]);
        }
        s += v;
    }
#pragma unroll
    for (int off = 32; off > 0; off >>= 1) s += __shfl_down(s, off, 64);
    if (lane == 0) out[p * 48 + f] = s * (1.0f / NN);
}

extern "C" void kernel_launch(void* const* d_in, const int* in_sizes, int n_in,
                              void* d_out, int out_size, void* d_ws, size_t ws_size,
                              hipStream_t stream) {
    const float* pc     = (const float*)d_in[0];
    const float* alphas = (const float*)d_in[1];
    float* outp = (float*)d_out;

    char* base = (char*)d_ws;
    size_t off = 0;
    auto carve = [&](size_t bytes) -> void* {
        void* r = base + off;
        off = (off + bytes + 255) & ~(size_t)255;
        return r;
    };
    float*     Xs  = (float*)carve((size_t)NPAIR * NN * 4 * sizeof(float));
    _Float16*  Xp  = (_Float16*)carve((size_t)NPAIR * 1024 * 8 * 2);
    float*     ihd = (float*)carve((size_t)NPAIR * NN * sizeof(float));
    _Float16*  XT  = (_Float16*)carve((size_t)NPAIR * 16 * NN * 2);
    _Float16*  UT  = (_Float16*)carve((size_t)NPAIR * 16 * NN * 2);
    _Float16*  pA  = (_Float16*)carve((size_t)NPAIR * 16 * NN * 2);
    _Float16*  pB  = (_Float16*)carve((size_t)NPAIR * 16 * NN * 2);
    _Float16*  pC  = (_Float16*)carve((size_t)NPAIR * 16 * NN * 2);
    _Float16*  pD  = (_Float16*)carve((size_t)NPAIR * 16 * NN * 2);
    float*     LT1 = (float*)carve((size_t)NPAIR * 5 * 16 * NN * sizeof(float));
    float*     LT2 = (float*)carve((size_t)NPAIR * 5 * 16 * NN * sizeof(float));

    dim3 gridS(NN / 32, NPAIR);   // singles: 64 x 16 = 1024 blocks (M=32)
    dim3 gridD(NN / 16, NPAIR);   // duals: 128 x 16 = 2048 blocks (M=16)

    initpack_k<<<dim3((NPAIR * NN) / 256), 256, 0, stream>>>(pc, alphas, Xs, XT, Xp);

    // phase 1: bank1 steps 1..8 (saves t=1,2,4,8 -> LT1 slots 0..3);
    // step 8 also emits UT (fused buildU).
    const _Float16* c1 = XT;
    int slot = 0;
    for (int step = 1; step <= 8; ++step) {
        _Float16* o1 = (c1 == pA) ? pB : pA;
        bool sv = (step & (step - 1)) == 0;
        float* lv = sv ? LT1 : nullptr;
        if (step == 1)
            apply_k<true, false, false><<<gridS, 512, 0, stream>>>(Xs, Xp, ihd,
                c1, o1, lv, slot, nullptr, nullptr, nullptr, 0, nullptr, nullptr);
        else if (step == 8)
            apply_k<false, false, true><<<gridS, 512, 0, stream>>>(Xs, Xp, ihd,
                c1, o1, lv, slot, nullptr, nullptr, nullptr, 0, LT1, UT);
        else
            apply_k<false, false, false><<<gridS, 512, 0, stream>>>(Xs, Xp, ihd,
                c1, o1, lv, slot, nullptr, nullptr, nullptr, 0, nullptr, nullptr);
        if (sv) ++slot;
        c1 = o1;
    }

    // phase 2: merged — bank1 steps 9..16 + bank2 steps 1..8 (shared evals)
    const _Float16* c2 = UT;
    int slot2 = 0;
    for (int i = 1; i <= 8; ++i) {
        _Float16* o1 = (c1 == pA) ? pB : pA;
        _Float16* o2 = (c2 == pC) ? pD : pC;
        float* lv1 = (i == 8) ? LT1 : nullptr;              // bank1 t=16 -> slot 4
        bool sv2 = (i & (i - 1)) == 0;                      // i = 1,2,4,8
        float* lv2 = sv2 ? LT2 : nullptr;
        apply_k<false, true, false><<<gridD, 512, 0, stream>>>(Xs, Xp, ihd,
            c1, o1, lv1, 4, c2, o2, lv2, slot2, nullptr, nullptr);
        if (sv2) ++slot2;
        c1 = o1; c2 = o2;
    }

    // phase 3: bank2 steps 9..16 (save t=16 -> LT2 slot 4)
    for (int i = 9; i <= 16; ++i) {
        _Float16* o2 = (c2 == pC) ? pD : pC;
        float* lv2 = (i == 16) ? LT2 : nullptr;
        apply_k<false, false, false><<<gridS, 512, 0, stream>>>(Xs, Xp, ihd,
            c2, o2, lv2, 4, nullptr, nullptr, nullptr, 0, nullptr, nullptr);
        c2 = o2;
    }

    reduce_k<<<dim3(48, NPAIR), 64, 0, stream>>>(Xs, LT1, LT2, outp);
}

// Round 21
// 483.807 us; speedup vs baseline: 1.2536x; 1.2536x over previous
//
#include <hip/hip_runtime.h>
#include <hip/hip_bf16.h>

// PointCloudNetPersistencePrediction — round 21: REVERT to R19 (best, 483us).
// R20 (dual s=1, M=16, 8 waves) REGRESSED to 606us: halving the m-subtile
// count doubles DS-reads/eval + X-staging frequency — below the tile
// efficiency knee. R19's (512,4)/s=2 dual is the optimum of that trade.
// Ladder: 3275 (R1) -> 2899 (occupancy) -> 1110 (LDS broadcast) -> 943
// (fused W->MFMA) -> 688 (lean eval+deg fold) -> 567 (packed fp16 pipe) ->
// 554 (8 waves) -> 484 (bank overlap) -> 483 (fusions). Remaining gap is
// ~9us x 25 sequential launch boundaries; grid.sync=35us (R15), DIY LLC
// sync incorrect (R16) -> structural plateau of this decomposition.

#define NN 2048
#define NPAIR 16

typedef _Float16 half8 __attribute__((ext_vector_type(8)));
typedef _Float16 f16x2 __attribute__((ext_vector_type(2)));
typedef float f32x4 __attribute__((ext_vector_type(4)));

extern "C" __device__ f16x2 __ocml_exp2_2f16(f16x2);   // packed v_exp_f16

#define C2F 0.28853900817779268f   //  0.2 * log2(e)
#define CWF -0.14426950408889634f  // -0.1 * log2(e)
#define NL2T 3.3219280948873623f   // -log2(0.1); qi' = qi + NL2T

// ---- init+pack fused: Xs fp32 [p][i][{x,y,z,q}]; XT fp16 [p][16][2048]
//      (row3 = ones -> deg via MFMA); Xp packed fp16 j-pair entries ----
__global__ __launch_bounds__(256) void initpack_k(const float* __restrict__ pc,
                                                  const float* __restrict__ alphas,
                                                  float* __restrict__ Xs,
                                                  _Float16* __restrict__ XT,
                                                  _Float16* __restrict__ Xp) {
    int gid = blockIdx.x * 256 + threadIdx.x;
    if (gid >= NPAIR * NN) return;
    int p = gid >> 11, i = gid & (NN - 1);
    int b = p >> 2, k = p & 3;
    const float* pcr = pc + ((size_t)b * NN + i) * 3;
    const float* al  = alphas + k * 3;
    float x = pcr[0] * al[0], y = pcr[1] * al[1], z = pcr[2] * al[2];
    float q = CWF * (x * x + y * y + z * z);
    float4 o; o.x = x; o.y = y; o.z = z; o.w = q;
    ((float4*)Xs)[gid] = o;
    _Float16* xt = XT + (size_t)p * 16 * NN + i;
    xt[0 * NN] = (_Float16)x;
    xt[1 * NN] = (_Float16)y;
    xt[2 * NN] = (_Float16)z;
    xt[3 * NN] = (_Float16)1.0f;
#pragma unroll
    for (int n = 4; n < 16; ++n) xt[n * NN] = (_Float16)0.f;
    _Float16* xp = Xp + ((size_t)p * 1024 + (i >> 1)) * 8 + (i & 1);
    xp[0] = (_Float16)x; xp[2] = (_Float16)y;
    xp[4] = (_Float16)z; xp[6] = (_Float16)q;
}

// ---- fused apply: out = f16(0.5*cur + ihd (x) (W@cur^T)^T).
// 512 thr = 8 K-waves (chunk 256); lane: s=2 m-subtiles; M=32; grid (64,16).
// DUAL: shared w-eval pass feeds two banks' MFMAs, single-pass epilogue.
// BUILDU: step-8 epilogue also emits this block's UT rows.
template<bool FIRST, bool DUAL, bool BUILDU>
__global__ __launch_bounds__(512, DUAL ? 4 : 8)
void apply_k(const float* __restrict__ Xs, const _Float16* __restrict__ Xp,
             float* __restrict__ ihd,
             const _Float16* __restrict__ cur1, _Float16* __restrict__ out1,
             float* __restrict__ lvl1, int t1,
             const _Float16* __restrict__ cur2, _Float16* __restrict__ out2,
             float* __restrict__ lvl2, int t2,
             const float* __restrict__ LT1u, _Float16* __restrict__ UTp) {
    constexpr int SMSZ = DUAL ? 8192 : 4352;       // floats
    __shared__ __align__(16) float smem[SMSZ];
    const int tid  = threadIdx.x;
    const int lane = tid & 63;
    const int wv   = tid >> 6;                     // K-group 0..7
    const int p    = blockIdx.y;
    const int m0   = blockIdx.x * 32;
    const int idx16 = lane & 15, quad = lane >> 4;

    {
        const float4* src = (const float4*)(Xp + (size_t)p * 8192);
        float4* dst = (float4*)smem;
        dst[tid]       = src[tid];
        dst[tid + 512] = src[tid + 512];
    }
    __syncthreads();

    f16x2 qi2[2], xx2[2], xy2[2], xz2[2];
#pragma unroll
    for (int s = 0; s < 2; ++s) {
        float4 v = *(const float4*)(Xs + ((size_t)p * NN + m0 + s * 16 + idx16) * 4);
        _Float16 q = (_Float16)(v.w + NL2T);
        _Float16 x = (_Float16)(C2F * v.x);
        _Float16 y = (_Float16)(C2F * v.y);
        _Float16 z = (_Float16)(C2F * v.z);
        qi2[s] = (f16x2){q, q}; xx2[s] = (f16x2){x, x};
        xy2[s] = (f16x2){y, y}; xz2[s] = (f16x2){z, z};
    }
    const f16x2 SC2 = (f16x2){(_Float16)32768.f, (_Float16)32768.f};

    const _Float16* bp1 = cur1 + ((size_t)p * 16 + idx16) * NN + wv * 256 + quad * 8;
    const _Float16* bp2 = DUAL ? cur2 + ((size_t)p * 16 + idx16) * NN + wv * 256 + quad * 8
                               : nullptr;
    f32x4 acc1[2] = {{0.f,0.f,0.f,0.f},{0.f,0.f,0.f,0.f}};
    f32x4 acc2[2] = {{0.f,0.f,0.f,0.f},{0.f,0.f,0.f,0.f}};

    for (int kc = 0; kc < 8; ++kc) {
        const int pb = wv * 128 + kc * 16 + quad * 4;  // j-pair entry base
        half8 bf1 = *(const half8*)(bp1 + kc * 32);
        half8 bf2;
        if (DUAL) bf2 = *(const half8*)(bp2 + kc * 32);
        union { f16x2 h2[4]; half8 h8; } af[2];
#pragma unroll
        for (int jp = 0; jp < 4; ++jp) {
            union { float4 f; f16x2 h[4]; } e;
            e.f = ((const float4*)smem)[pb + jp];      // {x2,y2,z2,q2} for 2 j
#pragma unroll
            for (int s = 0; s < 2; ++s) {
                f16x2 tv = qi2[s] + e.h[3];
                tv = __builtin_elementwise_fma(xx2[s], e.h[0], tv);
                tv = __builtin_elementwise_fma(xy2[s], e.h[1], tv);
                tv = __builtin_elementwise_fma(xz2[s], e.h[2], tv);
                // threshold folded into exp arg: t'<0 -> arg<=-24 -> exp2 = 0
                f16x2 u = __builtin_elementwise_min(tv, tv * SC2);
                af[s].h2[jp] = __ocml_exp2_2f16(u);    // = 10*w (2^3.32 fold)
            }
        }
#pragma unroll
        for (int s = 0; s < 2; ++s) {
            acc1[s] = __builtin_amdgcn_mfma_f32_16x16x32_f16(af[s].h8, bf1, acc1[s], 0, 0, 0);
            if (DUAL)
                acc2[s] = __builtin_amdgcn_mfma_f32_16x16x32_f16(af[s].h8, bf2, acc2[s], 0, 0, 0);
        }
    }

    // ---- epilogue ----
    const int n = tid & 15, rloc = tid >> 4;
    const int s2 = rloc >> 4, mloc = rloc & 15;
    const int base = s2 * 256 + (mloc >> 2) * 64 + (mloc & 3);
    const int row = m0 + rloc;
    float ihEff;
    if (!FIRST) ihEff = 0.1f * ihd[p * NN + row];

    __syncthreads();
#pragma unroll
    for (int s = 0; s < 2; ++s)
        *(f32x4*)&smem[wv * 512 + s * 256 + lane * 4] = acc1[s];
    if (DUAL) {
#pragma unroll
        for (int s = 0; s < 2; ++s)
            *(f32x4*)&smem[4096 + wv * 512 + s * 256 + lane * 4] = acc2[s];
    }
    __syncthreads();

    float o1v;
    {
        float sum = 0.f;                               // = 10*(W@B)
#pragma unroll
        for (int g = 0; g < 8; ++g) sum += smem[g * 512 + base + n * 4];
        if (FIRST) {
            float deg10 = 0.f;                         // = 10*deg
#pragma unroll
            for (int g = 0; g < 8; ++g) deg10 += smem[g * 512 + base + 12];
            float ih = 5.0f / deg10;                   // = 0.5/deg
            if (n == 3) ihd[p * NN + row] = ih;
            ihEff = 0.1f * ih;
        }
        float cv = (float)cur1[((size_t)p * 16 + n) * NN + row];
        o1v = 0.5f * cv + ihEff * sum;
        out1[((size_t)p * 16 + n) * NN + row] = (_Float16)o1v;
        if (lvl1) lvl1[(((size_t)p * 5 + t1) * 16 + n) * NN + row] = o1v;
    }
    if (DUAL) {
        float sum = 0.f;
#pragma unroll
        for (int g = 0; g < 8; ++g) sum += smem[4096 + g * 512 + base + n * 4];
        float cv = (float)cur2[((size_t)p * 16 + n) * NN + row];
        float o = 0.5f * cv + ihEff * sum;
        out2[((size_t)p * 16 + n) * NN + row] = (_Float16)o;
        if (lvl2) lvl2[(((size_t)p * 5 + t2) * 16 + n) * NN + row] = o;
    }
    if (BUILDU) {
        // stash fresh t=8 (cols 0-2) then emit this block's UT rows
        if (n < 3) smem[4096 + n * 32 + rloc] = o1v;
        __syncthreads();
        _Float16 uv = (_Float16)0.f;
        if (n < 12) {
            const int jw = n / 3, c = n - 3 * jw;
            float a = (jw == 0) ? Xs[((size_t)p * NN + row) * 4 + c]
                                : LT1u[(((size_t)p * 5 + (jw - 1)) * 16 + c) * NN + row];
            float bb = (jw == 3) ? smem[4096 + c * 32 + rloc]
                                 : LT1u[(((size_t)p * 5 + jw) * 16 + c) * NN + row];
            uv = (_Float16)fabsf(a - bb);
        }
        UTp[((size_t)p * 16 + n) * NN + row] = uv;
    }
}

// ---- final mean over N of 48 features (levels [p][t][n][m]) ----
__global__ __launch_bounds__(64) void reduce_k(const float* __restrict__ Xs,
                                               const float* __restrict__ LT1,
                                               const float* __restrict__ LT2,
                                               float* __restrict__ out) {
    int f = blockIdx.x, p = blockIdx.y, lane = threadIdx.x;
    const float* l1 = LT1 + (size_t)p * 5 * 16 * NN;
    const float* l2 = LT2 + (size_t)p * 5 * 16 * NN;
    float s = 0.f;
    for (int m = lane; m < NN; m += 64) {
        float v;
        if (f < 3) {
            v = l1[((size_t)4 * 16 + f) * NN + m];
        } else if (f < 18) {
            int j = (f - 3) / 3, c = (f - 3) % 3;
            float a = (j == 0) ? Xs[((size_t)p * NN + m) * 4 + c]
                               : l1[((size_t)(j - 1) * 16 + c) * NN + m];
            float b = l1[((size_t)j * 16 + c) * NN + m];
            v = fabsf(a - b);
        } else {
            int gg = f - 18, j2, uc;
            if (gg < 3)       { j2 = 1; uc = gg; }
            else if (gg < 9)  { j2 = 2; uc = gg - 3; }
            else if (gg < 18) { j2 = 3; uc = gg - 9; }
            else              { j2 = 4; uc = gg - 18; }
            v = fabsf(l2[((size_t)(j2 - 1) * 16 + uc) * NN + m]
                    - l2[((size_t)j2 * 16 + uc) * NN + m]);
        }
        s += v;
    }
#pragma unroll
    for (int off = 32; off > 0; off >>= 1) s += __shfl_down(s, off, 64);
    if (lane == 0) out[p * 48 + f] = s * (1.0f / NN);
}

extern "C" void kernel_launch(void* const* d_in, const int* in_sizes, int n_in,
                              void* d_out, int out_size, void* d_ws, size_t ws_size,
                              hipStream_t stream) {
    const float* pc     = (const float*)d_in[0];
    const float* alphas = (const float*)d_in[1];
    float* outp = (float*)d_out;

    char* base = (char*)d_ws;
    size_t off = 0;
    auto carve = [&](size_t bytes) -> void* {
        void* r = base + off;
        off = (off + bytes + 255) & ~(size_t)255;
        return r;
    };
    float*     Xs  = (float*)carve((size_t)NPAIR * NN * 4 * sizeof(float));
    _Float16*  Xp  = (_Float16*)carve((size_t)NPAIR * 1024 * 8 * 2);
    float*     ihd = (float*)carve((size_t)NPAIR * NN * sizeof(float));
    _Float16*  XT  = (_Float16*)carve((size_t)NPAIR * 16 * NN * 2);
    _Float16*  UT  = (_Float16*)carve((size_t)NPAIR * 16 * NN * 2);
    _Float16*  pA  = (_Float16*)carve((size_t)NPAIR * 16 * NN * 2);
    _Float16*  pB  = (_Float16*)carve((size_t)NPAIR * 16 * NN * 2);
    _Float16*  pC  = (_Float16*)carve((size_t)NPAIR * 16 * NN * 2);
    _Float16*  pD  = (_Float16*)carve((size_t)NPAIR * 16 * NN * 2);
    float*     LT1 = (float*)carve((size_t)NPAIR * 5 * 16 * NN * sizeof(float));
    float*     LT2 = (float*)carve((size_t)NPAIR * 5 * 16 * NN * sizeof(float));

    dim3 gridA(NN / 32, NPAIR);   // 64 x 16 = 1024 blocks

    initpack_k<<<dim3((NPAIR * NN) / 256), 256, 0, stream>>>(pc, alphas, Xs, XT, Xp);

    // phase 1: bank1 steps 1..8 (saves t=1,2,4,8 -> LT1 slots 0..3);
    // step 8 also emits UT (fused buildU).
    const _Float16* c1 = XT;
    int slot = 0;
    for (int step = 1; step <= 8; ++step) {
        _Float16* o1 = (c1 == pA) ? pB : pA;
        bool sv = (step & (step - 1)) == 0;
        float* lv = sv ? LT1 : nullptr;
        if (step == 1)
            apply_k<true, false, false><<<gridA, 512, 0, stream>>>(Xs, Xp, ihd,
                c1, o1, lv, slot, nullptr, nullptr, nullptr, 0, nullptr, nullptr);
        else if (step == 8)
            apply_k<false, false, true><<<gridA, 512, 0, stream>>>(Xs, Xp, ihd,
                c1, o1, lv, slot, nullptr, nullptr, nullptr, 0, LT1, UT);
        else
            apply_k<false, false, false><<<gridA, 512, 0, stream>>>(Xs, Xp, ihd,
                c1, o1, lv, slot, nullptr, nullptr, nullptr, 0, nullptr, nullptr);
        if (sv) ++slot;
        c1 = o1;
    }

    // phase 2: merged — bank1 steps 9..16 + bank2 steps 1..8 (shared evals)
    const _Float16* c2 = UT;
    int slot2 = 0;
    for (int i = 1; i <= 8; ++i) {
        _Float16* o1 = (c1 == pA) ? pB : pA;
        _Float16* o2 = (c2 == pC) ? pD : pC;
        float* lv1 = (i == 8) ? LT1 : nullptr;              // bank1 t=16 -> slot 4
        bool sv2 = (i & (i - 1)) == 0;                      // i = 1,2,4,8
        float* lv2 = sv2 ? LT2 : nullptr;
        apply_k<false, true, false><<<gridA, 512, 0, stream>>>(Xs, Xp, ihd,
            c1, o1, lv1, 4, c2, o2, lv2, slot2, nullptr, nullptr);
        if (sv2) ++slot2;
        c1 = o1; c2 = o2;
    }

    // phase 3: bank2 steps 9..16 (save t=16 -> LT2 slot 4)
    for (int i = 9; i <= 16; ++i) {
        _Float16* o2 = (c2 == pC) ? pD : pC;
        float* lv2 = (i == 16) ? LT2 : nullptr;
        apply_k<false, false, false><<<gridA, 512, 0, stream>>>(Xs, Xp, ihd,
            c2, o2, lv2, 4, nullptr, nullptr, nullptr, 0, nullptr, nullptr);
        c2 = o2;
    }

    reduce_k<<<dim3(48, NPAIR), 64, 0, stream>>>(Xs, LT1, LT2, outp);
}